// Round 1
// baseline (1496.721 us; speedup 1.0000x reference)
//
#include <hip/hip_runtime.h>
#include <math.h>

#define SEQ    2048
#define DMODEL 1024
#define NHEADS 16
#define DHEAD  64
#define NBATCH 2

// ---------------------------------------------------------------------------
// GEMM: C[M,N] = A[M,K] @ W[K,N] + bias[N]
// fp32, 128x128 block tile, BK=16, 256 threads, 8x8 per thread (4+4 split).
// A row-major, W row-major.
// ---------------------------------------------------------------------------
__global__ __launch_bounds__(256)
void gemm_bias_kernel(const float* __restrict__ A, const float* __restrict__ W,
                      const float* __restrict__ bias, float* __restrict__ C,
                      int M, int N, int K) {
    __shared__ float As[16][132];   // A tile transposed: As[k][row]
    __shared__ float Bs[16][132];   // B tile: Bs[k][col]

    const int tid = threadIdx.x;
    const int bm  = blockIdx.y * 128;
    const int bn  = blockIdx.x * 128;
    const int ty  = tid >> 4;   // 0..15
    const int tx  = tid & 15;   // 0..15

    float acc[8][8];
#pragma unroll
    for (int i = 0; i < 8; ++i)
#pragma unroll
        for (int j = 0; j < 8; ++j) acc[i][j] = 0.f;

    for (int k0 = 0; k0 < K; k0 += 16) {
        // Load A tile 128x16 (float4 along k), store transposed.
#pragma unroll
        for (int it = 0; it < 2; ++it) {
            int slot = tid + it * 256;          // 0..511
            int row  = slot >> 2;               // 0..127
            int c4   = (slot & 3) << 2;         // 0,4,8,12
            float4 av = *reinterpret_cast<const float4*>(
                &A[(size_t)(bm + row) * K + k0 + c4]);
            As[c4 + 0][row] = av.x;
            As[c4 + 1][row] = av.y;
            As[c4 + 2][row] = av.z;
            As[c4 + 3][row] = av.w;
        }
        // Load B tile 16x128 (float4 along n).
#pragma unroll
        for (int it = 0; it < 2; ++it) {
            int slot = tid + it * 256;          // 0..511
            int kr   = slot >> 5;               // 0..15
            int n4   = (slot & 31) << 2;        // 0..124
            *reinterpret_cast<float4*>(&Bs[kr][n4]) =
                *reinterpret_cast<const float4*>(
                    &W[(size_t)(k0 + kr) * N + bn + n4]);
        }
        __syncthreads();

#pragma unroll
        for (int kk = 0; kk < 16; ++kk) {
            float a[8], b[8];
            float4 t0 = *reinterpret_cast<const float4*>(&As[kk][ty * 4]);
            float4 t1 = *reinterpret_cast<const float4*>(&As[kk][64 + ty * 4]);
            a[0] = t0.x; a[1] = t0.y; a[2] = t0.z; a[3] = t0.w;
            a[4] = t1.x; a[5] = t1.y; a[6] = t1.z; a[7] = t1.w;
            float4 u0 = *reinterpret_cast<const float4*>(&Bs[kk][tx * 4]);
            float4 u1 = *reinterpret_cast<const float4*>(&Bs[kk][64 + tx * 4]);
            b[0] = u0.x; b[1] = u0.y; b[2] = u0.z; b[3] = u0.w;
            b[4] = u1.x; b[5] = u1.y; b[6] = u1.z; b[7] = u1.w;
#pragma unroll
            for (int i = 0; i < 8; ++i)
#pragma unroll
                for (int j = 0; j < 8; ++j) acc[i][j] += a[i] * b[j];
        }
        __syncthreads();
    }

    // Epilogue: bias add + store.
    float b0[4], b1[4];
#pragma unroll
    for (int j = 0; j < 4; ++j) {
        b0[j] = bias[bn + tx * 4 + j];
        b1[j] = bias[bn + 64 + tx * 4 + j];
    }
#pragma unroll
    for (int i = 0; i < 8; ++i) {
        int row = bm + ((i < 4) ? (ty * 4 + i) : (64 + ty * 4 + (i - 4)));
        float4 o0, o1;
        o0.x = acc[i][0] + b0[0]; o0.y = acc[i][1] + b0[1];
        o0.z = acc[i][2] + b0[2]; o0.w = acc[i][3] + b0[3];
        o1.x = acc[i][4] + b1[0]; o1.y = acc[i][5] + b1[1];
        o1.z = acc[i][6] + b1[2]; o1.w = acc[i][7] + b1[3];
        *reinterpret_cast<float4*>(&C[(size_t)row * N + bn + tx * 4])      = o0;
        *reinterpret_cast<float4*>(&C[(size_t)row * N + bn + 64 + tx * 4]) = o1;
    }
}

// ---------------------------------------------------------------------------
// Causal flash attention, fp32.
// Q,K,V,CTX layout: [B, S, H*DH] (head slice contiguous).
// Block = 256 threads (4 waves). Each wave: 32 query rows x 2 lanes/row.
// Lane pair (l, l^32) splits the 64 head dims 32/32; partial dot combined
// with __shfl_xor(...,32). K/V staged in LDS, 64 keys per tile.
// Online softmax: rescale only when the running max changes.
// ---------------------------------------------------------------------------
__global__ __launch_bounds__(256)
void attn_kernel(const float* __restrict__ Q, const float* __restrict__ K,
                 const float* __restrict__ V, float* __restrict__ CTX) {
    __shared__ float Ks[64][64];
    __shared__ float Vs[64][64];

    const int tiles_per_bh = SEQ / 128;              // 16
    const int bh = blockIdx.x / tiles_per_bh;        // 0..31
    const int rb = blockIdx.x % tiles_per_bh;        // query row block
    const int b  = bh >> 4;                          // /NHEADS
    const int h  = bh & 15;

    const int tid   = threadIdx.x;
    const int wave  = tid >> 6;
    const int lane  = tid & 63;
    const int rloc  = lane & 31;
    const int half  = lane >> 5;
    const int row   = rb * 128 + wave * 32 + rloc;   // query row (0..S-1)
    const int dbase = half * 32;

    // Load my half of the query row into registers.
    float q[32];
    {
        const float* qp = Q + (size_t)(b * SEQ + row) * DMODEL + h * DHEAD + dbase;
#pragma unroll
        for (int i = 0; i < 32; i += 4) {
            float4 v4 = *reinterpret_cast<const float4*>(qp + i);
            q[i] = v4.x; q[i + 1] = v4.y; q[i + 2] = v4.z; q[i + 3] = v4.w;
        }
    }

    float acc[32];
#pragma unroll
    for (int i = 0; i < 32; ++i) acc[i] = 0.f;
    float m = -1e30f, l = 0.f;

    const float scale = 0.125f;   // 1/sqrt(64)
    const int jmax = rb * 128 + 128;   // exclusive key bound for this block

    for (int j0 = 0; j0 < jmax; j0 += 64) {
        // Stage 64 keys + values (64 x 64 floats each).
        {
            int r = tid >> 2;                 // 0..63
            int c = (tid & 3) << 4;           // 0,16,32,48
            const float* kp = K + (size_t)(b * SEQ + j0 + r) * DMODEL + h * DHEAD + c;
            const float* vp = V + (size_t)(b * SEQ + j0 + r) * DMODEL + h * DHEAD + c;
#pragma unroll
            for (int u = 0; u < 16; u += 4) {
                *reinterpret_cast<float4*>(&Ks[r][c + u]) =
                    *reinterpret_cast<const float4*>(kp + u);
                *reinterpret_cast<float4*>(&Vs[r][c + u]) =
                    *reinterpret_cast<const float4*>(vp + u);
            }
        }
        __syncthreads();

        int jend = row - j0 + 1;              // causal: keys j0 .. row
        if (jend > 64) jend = 64;
        for (int jj = 0; jj < jend; ++jj) {
            float partial = 0.f;
#pragma unroll
            for (int i = 0; i < 32; i += 4) {
                float4 kv = *reinterpret_cast<const float4*>(&Ks[jj][dbase + i]);
                partial += q[i] * kv.x + q[i + 1] * kv.y +
                           q[i + 2] * kv.z + q[i + 3] * kv.w;
            }
            float s = (partial + __shfl_xor(partial, 32, 64)) * scale;
            if (s <= m) {
                float p = __expf(s - m);
                l += p;
#pragma unroll
                for (int i = 0; i < 32; i += 4) {
                    float4 vv = *reinterpret_cast<const float4*>(&Vs[jj][dbase + i]);
                    acc[i]     += p * vv.x;
                    acc[i + 1] += p * vv.y;
                    acc[i + 2] += p * vv.z;
                    acc[i + 3] += p * vv.w;
                }
            } else {
                float cor = __expf(m - s);
                m = s;
                l = l * cor + 1.f;
#pragma unroll
                for (int i = 0; i < 32; i += 4) {
                    float4 vv = *reinterpret_cast<const float4*>(&Vs[jj][dbase + i]);
                    acc[i]     = acc[i]     * cor + vv.x;
                    acc[i + 1] = acc[i + 1] * cor + vv.y;
                    acc[i + 2] = acc[i + 2] * cor + vv.z;
                    acc[i + 3] = acc[i + 3] * cor + vv.w;
                }
            }
        }
        __syncthreads();
    }

    const float inv = 1.f / l;
    float* op = CTX + (size_t)(b * SEQ + row) * DMODEL + h * DHEAD + dbase;
#pragma unroll
    for (int i = 0; i < 32; i += 4) {
        float4 o;
        o.x = acc[i] * inv; o.y = acc[i + 1] * inv;
        o.z = acc[i + 2] * inv; o.w = acc[i + 3] * inv;
        *reinterpret_cast<float4*>(op + i) = o;
    }
}

// ---------------------------------------------------------------------------
extern "C" void kernel_launch(void* const* d_in, const int* in_sizes, int n_in,
                              void* d_out, int out_size, void* d_ws, size_t ws_size,
                              hipStream_t stream) {
    const float* hs = (const float*)d_in[0];
    const float* Wq = (const float*)d_in[1];
    const float* bq = (const float*)d_in[2];
    const float* Wk = (const float*)d_in[3];
    const float* bk = (const float*)d_in[4];
    const float* Wv = (const float*)d_in[5];
    const float* bv = (const float*)d_in[6];
    const float* Wo = (const float*)d_in[7];
    const float* bo = (const float*)d_in[8];
    float* out = (float*)d_out;

    const size_t NTOK = (size_t)NBATCH * SEQ;        // 4096
    float* ws = (float*)d_ws;
    float* Qb = ws;
    float* Kb = ws + 1 * NTOK * DMODEL;
    float* Vb = ws + 2 * NTOK * DMODEL;
    float* Cb = ws + 3 * NTOK * DMODEL;              // 64 MB total

    dim3 gg(DMODEL / 128, NTOK / 128);               // (8, 32)
    gemm_bias_kernel<<<gg, 256, 0, stream>>>(hs, Wq, bq, Qb, (int)NTOK, DMODEL, DMODEL);
    gemm_bias_kernel<<<gg, 256, 0, stream>>>(hs, Wk, bk, Kb, (int)NTOK, DMODEL, DMODEL);
    gemm_bias_kernel<<<gg, 256, 0, stream>>>(hs, Wv, bv, Vb, (int)NTOK, DMODEL, DMODEL);

    attn_kernel<<<NBATCH * NHEADS * (SEQ / 128), 256, 0, stream>>>(Qb, Kb, Vb, Cb);

    gemm_bias_kernel<<<gg, 256, 0, stream>>>(Cb, Wo, bo, out, (int)NTOK, DMODEL, DMODEL);
}

// Round 2
// 636.924 us; speedup vs baseline: 2.3499x; 2.3499x over previous
//
#include <hip/hip_runtime.h>
#include <math.h>

#define SEQ    2048
#define DMODEL 1024
#define NHEADS 16
#define DHEAD  64
#define NBATCH 2

typedef __attribute__((ext_vector_type(8))) short     bf16x8;
typedef __attribute__((ext_vector_type(4))) float     f32x4;
typedef __attribute__((ext_vector_type(4))) unsigned short ushort4v;

__device__ __forceinline__ unsigned short f2bf(float f) {
    union { float f; unsigned u; } v; v.f = f;
    unsigned r = (v.u + 0x7FFF + ((v.u >> 16) & 1)) >> 16;
    return (unsigned short)r;
}

// ---------------------------------------------------------------------------
// GEMM: C[M,N] = A[M,K] @ W[K,N] + bias[N]  (fp32, unchanged from R1)
// ---------------------------------------------------------------------------
__global__ __launch_bounds__(256)
void gemm_bias_kernel(const float* __restrict__ A, const float* __restrict__ W,
                      const float* __restrict__ bias, float* __restrict__ C,
                      int M, int N, int K) {
    __shared__ float As[16][132];
    __shared__ float Bs[16][132];

    const int tid = threadIdx.x;
    const int bm  = blockIdx.y * 128;
    const int bn  = blockIdx.x * 128;
    const int ty  = tid >> 4;
    const int tx  = tid & 15;

    float acc[8][8];
#pragma unroll
    for (int i = 0; i < 8; ++i)
#pragma unroll
        for (int j = 0; j < 8; ++j) acc[i][j] = 0.f;

    for (int k0 = 0; k0 < K; k0 += 16) {
#pragma unroll
        for (int it = 0; it < 2; ++it) {
            int slot = tid + it * 256;
            int row  = slot >> 2;
            int c4   = (slot & 3) << 2;
            float4 av = *reinterpret_cast<const float4*>(
                &A[(size_t)(bm + row) * K + k0 + c4]);
            As[c4 + 0][row] = av.x;
            As[c4 + 1][row] = av.y;
            As[c4 + 2][row] = av.z;
            As[c4 + 3][row] = av.w;
        }
#pragma unroll
        for (int it = 0; it < 2; ++it) {
            int slot = tid + it * 256;
            int kr   = slot >> 5;
            int n4   = (slot & 31) << 2;
            *reinterpret_cast<float4*>(&Bs[kr][n4]) =
                *reinterpret_cast<const float4*>(
                    &W[(size_t)(k0 + kr) * N + bn + n4]);
        }
        __syncthreads();

#pragma unroll
        for (int kk = 0; kk < 16; ++kk) {
            float a[8], b[8];
            float4 t0 = *reinterpret_cast<const float4*>(&As[kk][ty * 4]);
            float4 t1 = *reinterpret_cast<const float4*>(&As[kk][64 + ty * 4]);
            a[0] = t0.x; a[1] = t0.y; a[2] = t0.z; a[3] = t0.w;
            a[4] = t1.x; a[5] = t1.y; a[6] = t1.z; a[7] = t1.w;
            float4 u0 = *reinterpret_cast<const float4*>(&Bs[kk][tx * 4]);
            float4 u1 = *reinterpret_cast<const float4*>(&Bs[kk][64 + tx * 4]);
            b[0] = u0.x; b[1] = u0.y; b[2] = u0.z; b[3] = u0.w;
            b[4] = u1.x; b[5] = u1.y; b[6] = u1.z; b[7] = u1.w;
#pragma unroll
            for (int i = 0; i < 8; ++i)
#pragma unroll
                for (int j = 0; j < 8; ++j) acc[i][j] += a[i] * b[j];
        }
        __syncthreads();
    }

    float b0[4], b1[4];
#pragma unroll
    for (int j = 0; j < 4; ++j) {
        b0[j] = bias[bn + tx * 4 + j];
        b1[j] = bias[bn + 64 + tx * 4 + j];
    }
#pragma unroll
    for (int i = 0; i < 8; ++i) {
        int row = bm + ((i < 4) ? (ty * 4 + i) : (64 + ty * 4 + (i - 4)));
        float4 o0, o1;
        o0.x = acc[i][0] + b0[0]; o0.y = acc[i][1] + b0[1];
        o0.z = acc[i][2] + b0[2]; o0.w = acc[i][3] + b0[3];
        o1.x = acc[i][4] + b1[0]; o1.y = acc[i][5] + b1[1];
        o1.z = acc[i][6] + b1[2]; o1.w = acc[i][7] + b1[3];
        *reinterpret_cast<float4*>(&C[(size_t)row * N + bn + tx * 4])      = o0;
        *reinterpret_cast<float4*>(&C[(size_t)row * N + bn + 64 + tx * 4]) = o1;
    }
}

// ---------------------------------------------------------------------------
// Cast fp32 [B,S,H*64] -> bf16 [B,H,S,64], optional scale (fold 1/sqrt(Dh)
// into Q). Fully coalesced both sides. 1M threads, 4 elems each.
// ---------------------------------------------------------------------------
__global__ __launch_bounds__(256)
void qk_cast_kernel(const float* __restrict__ in, unsigned short* __restrict__ out,
                    float scale) {
    const unsigned gid = blockIdx.x * 256 + threadIdx.x;   // 0 .. 1M-1
    const unsigned u   = gid * 4;                          // output flat index
    const unsigned d   = u & 63;
    const unsigned s   = (u >> 6) & (SEQ - 1);
    const unsigned bh  = u >> 17;                          // /(64*2048)
    const unsigned b   = bh >> 4;
    const unsigned h   = bh & 15;
    const size_t in_off = ((size_t)(b * SEQ + s)) * DMODEL + h * DHEAD + d;
    float4 v = *reinterpret_cast<const float4*>(in + in_off);
    ushort4v o;
    o.x = f2bf(v.x * scale); o.y = f2bf(v.y * scale);
    o.z = f2bf(v.z * scale); o.w = f2bf(v.w * scale);
    *reinterpret_cast<ushort4v*>(out + u) = o;
}

// ---------------------------------------------------------------------------
// Transpose V: fp32 [B,S,H*64] -> bf16 [B,H,64,S] via LDS 64x64 tiles.
// One block per (b,h,s-tile).
// ---------------------------------------------------------------------------
__global__ __launch_bounds__(256)
void v_transpose_kernel(const float* __restrict__ in, unsigned short* __restrict__ out) {
    __shared__ float tile[64][65];
    const int stile = blockIdx.x & (SEQ / 64 - 1);         // 0..31
    const int bh    = blockIdx.x >> 5;                     // 0..31
    const int b     = bh >> 4;
    const int h     = bh & 15;
    const int s0    = stile * 64;
    const int tid   = threadIdx.x;

    // Load 64x64 fp32 tile, coalesced along d.
#pragma unroll
    for (int r = 0; r < 4; ++r) {
        int sl = r * 16 + (tid >> 4);
        int dl = (tid & 15) * 4;
        float4 v = *reinterpret_cast<const float4*>(
            &in[((size_t)(b * SEQ + s0 + sl)) * DMODEL + h * DHEAD + dl]);
        tile[sl][dl + 0] = v.x; tile[sl][dl + 1] = v.y;
        tile[sl][dl + 2] = v.z; tile[sl][dl + 3] = v.w;
    }
    __syncthreads();

    // Store transposed: out[(bh*64 + d)*SEQ + s], 16 bf16 per thread.
    const int d   = tid >> 2;
    const int slb = (tid & 3) * 16;
    unsigned short tmp[16];
#pragma unroll
    for (int k = 0; k < 16; ++k) tmp[k] = f2bf(tile[slb + k][d]);
    unsigned short* op = out + ((size_t)(bh * DHEAD + d)) * SEQ + s0 + slb;
    *reinterpret_cast<bf16x8*>(op)     = *reinterpret_cast<bf16x8*>(&tmp[0]);
    *reinterpret_cast<bf16x8*>(op + 8) = *reinterpret_cast<bf16x8*>(&tmp[8]);
}

// ---------------------------------------------------------------------------
// Causal flash attention with bf16 MFMA (16x16x32), fp32 accumulate.
// Q,K: bf16 [B,H,S,64] (Q pre-scaled by 1/8). Vt: bf16 [B,H,64,S].
// Out CTX: fp32 [B,S,H*64].
// Block = 4 waves; wave w owns 32 q-rows; K/V tiles of 64 staged in LDS
// with XOR swizzle byte ^= ((row&7)<<4). P repacked via per-wave LDS.
// ---------------------------------------------------------------------------
__global__ __launch_bounds__(256)
void attn_mfma_kernel(const unsigned short* __restrict__ Qg,
                      const unsigned short* __restrict__ Kg,
                      const unsigned short* __restrict__ Vtg,
                      float* __restrict__ CTX) {
    __shared__ __align__(16) unsigned short Ks[64 * 64];   // [key][dim], swizzled
    __shared__ __align__(16) unsigned short Vt[64 * 64];   // [dim][key], swizzled
    __shared__ __align__(16) unsigned short Pl[4][32 * 64];// per-wave [row][key], swizzled

    const int tiles = SEQ / 128;                     // 16
    const int bh = blockIdx.x / tiles;
    const int rb = (tiles - 1) - (blockIdx.x % tiles);   // big blocks first
    const int b  = bh >> 4;
    const int h  = bh & 15;
    const int r0 = rb * 128;
    const int tid  = threadIdx.x;
    const int w    = tid >> 6;
    const int lane = tid & 63;
    const int lrow = lane & 15;   // A-frag row / B-frag col
    const int lk   = lane >> 4;   // k-slice group 0..3
    const int wr0  = r0 + w * 32; // wave's first q row

    const unsigned short* Qb = Qg + ((size_t)bh * SEQ) * DHEAD;
    const unsigned short* Kb = Kg + ((size_t)bh * SEQ) * DHEAD;
    const unsigned short* Vb = Vtg + ((size_t)bh * DHEAD) * SEQ;

    // Q fragments: q[mg][ks]: rows wr0+mg*16+lrow, dims ks*32 + lk*8 ..+7
    bf16x8 q[2][2];
#pragma unroll
    for (int mg = 0; mg < 2; ++mg)
#pragma unroll
        for (int ks = 0; ks < 2; ++ks)
            q[mg][ks] = *reinterpret_cast<const bf16x8*>(
                Qb + (size_t)(wr0 + mg * 16 + lrow) * DHEAD + ks * 32 + lk * 8);

    f32x4 O[2][4];
    float m[2][4], l[2][4];
#pragma unroll
    for (int mg = 0; mg < 2; ++mg)
#pragma unroll
        for (int j = 0; j < 4; ++j) { m[mg][j] = -1e30f; l[mg][j] = 0.f; }
#pragma unroll
    for (int mg = 0; mg < 2; ++mg)
#pragma unroll
        for (int ng = 0; ng < 4; ++ng) O[mg][ng] = (f32x4){0.f, 0.f, 0.f, 0.f};

    const int ntile = (r0 + 128) / 64;
    for (int t = 0; t < ntile; ++t) {
        const int j0 = t * 64;
        // ---- stage K tile [key][dim] and Vt tile [dim][key], swizzled ----
        {
            const int row = tid >> 2;            // key for Ks, dim for Vt
            const int c0  = (tid & 3) * 16;      // element chunk base
            const unsigned short* kp = Kb + (size_t)(j0 + row) * DHEAD + c0;
            const unsigned short* vp = Vb + (size_t)row * SEQ + j0 + c0;
#pragma unroll
            for (int u2 = 0; u2 < 2; ++u2) {
                bf16x8 kv = *reinterpret_cast<const bf16x8*>(kp + u2 * 8);
                bf16x8 vv = *reinterpret_cast<const bf16x8*>(vp + u2 * 8);
                int boff = row * 128 + (((c0 + u2 * 8) * 2) ^ ((row & 7) << 4));
                *reinterpret_cast<bf16x8*>((char*)Ks + boff) = kv;
                *reinterpret_cast<bf16x8*>((char*)Vt + boff) = vv;
            }
        }
        __syncthreads();

        if (j0 <= wr0 + 31) {                    // wave has unmasked keys here
            // ---- QK^T: S[mg][kg], rows=(lk*4+j), cols=keys kg*16+lrow ----
            f32x4 S[2][4];
#pragma unroll
            for (int mg = 0; mg < 2; ++mg)
#pragma unroll
                for (int kg = 0; kg < 4; ++kg) S[mg][kg] = (f32x4){0.f, 0.f, 0.f, 0.f};
#pragma unroll
            for (int kg = 0; kg < 4; ++kg) {
                const int key = kg * 16 + lrow;
#pragma unroll
                for (int ks = 0; ks < 2; ++ks) {
                    int boff = key * 128 + ((ks * 64 + lk * 16) ^ ((key & 7) << 4));
                    bf16x8 kf = *reinterpret_cast<const bf16x8*>((char*)Ks + boff);
                    S[0][kg] = __builtin_amdgcn_mfma_f32_16x16x32_bf16(q[0][ks], kf, S[0][kg], 0, 0, 0);
                    S[1][kg] = __builtin_amdgcn_mfma_f32_16x16x32_bf16(q[1][ks], kf, S[1][kg], 0, 0, 0);
                }
            }
            // ---- causal mask (diagonal tiles only) ----
            if (j0 + 63 > wr0) {
#pragma unroll
                for (int mg = 0; mg < 2; ++mg)
#pragma unroll
                    for (int kg = 0; kg < 4; ++kg) {
                        const int keyabs = j0 + kg * 16 + lrow;
#pragma unroll
                        for (int j = 0; j < 4; ++j) {
                            int rowabs = wr0 + mg * 16 + lk * 4 + j;
                            if (keyabs > rowabs) S[mg][kg][j] = -1e30f;
                        }
                    }
            }
            // ---- online softmax + P->bf16->LDS ----
#pragma unroll
            for (int mg = 0; mg < 2; ++mg) {
                float rmax[4], rsum[4], cor[4];
#pragma unroll
                for (int j = 0; j < 4; ++j)
                    rmax[j] = fmaxf(fmaxf(S[mg][0][j], S[mg][1][j]),
                                    fmaxf(S[mg][2][j], S[mg][3][j]));
#pragma unroll
                for (int d = 1; d < 16; d <<= 1)
#pragma unroll
                    for (int j = 0; j < 4; ++j)
                        rmax[j] = fmaxf(rmax[j], __shfl_xor(rmax[j], d));
#pragma unroll
                for (int j = 0; j < 4; ++j) {
                    float mn = fmaxf(m[mg][j], rmax[j]);
                    cor[j] = __expf(m[mg][j] - mn);
                    m[mg][j] = mn;
                    rsum[j] = 0.f;
                }
#pragma unroll
                for (int kg = 0; kg < 4; ++kg)
#pragma unroll
                    for (int j = 0; j < 4; ++j) {
                        float p = __expf(S[mg][kg][j] - m[mg][j]);
                        S[mg][kg][j] = p;
                        rsum[j] += p;
                    }
#pragma unroll
                for (int d = 1; d < 16; d <<= 1)
#pragma unroll
                    for (int j = 0; j < 4; ++j)
                        rsum[j] += __shfl_xor(rsum[j], d);
#pragma unroll
                for (int j = 0; j < 4; ++j)
                    l[mg][j] = l[mg][j] * cor[j] + rsum[j];
#pragma unroll
                for (int ng = 0; ng < 4; ++ng)
#pragma unroll
                    for (int j = 0; j < 4; ++j)
                        O[mg][ng][j] *= cor[j];
                // write P (bf16) to per-wave LDS, swizzled
#pragma unroll
                for (int kg = 0; kg < 4; ++kg) {
                    const int key = kg * 16 + lrow;
#pragma unroll
                    for (int j = 0; j < 4; ++j) {
                        int rl = mg * 16 + lk * 4 + j;
                        int boff = rl * 128 + ((key * 2) ^ ((rl & 7) << 4));
                        *reinterpret_cast<unsigned short*>((char*)&Pl[w][0] + boff)
                            = f2bf(S[mg][kg][j]);
                    }
                }
            }
            asm volatile("" ::: "memory");   // keep P reads after P writes (in-order DS)
            // ---- PV: O[mg][ng] += P(16x32) * V(32x16) over 2 key slices ----
#pragma unroll
            for (int ks2 = 0; ks2 < 2; ++ks2) {
                bf16x8 pa[2];
#pragma unroll
                for (int mg = 0; mg < 2; ++mg) {
                    int rl = mg * 16 + lrow;
                    int boff = rl * 128 + ((ks2 * 64 + lk * 16) ^ ((rl & 7) << 4));
                    pa[mg] = *reinterpret_cast<const bf16x8*>((char*)&Pl[w][0] + boff);
                }
#pragma unroll
                for (int ng = 0; ng < 4; ++ng) {
                    int dim = ng * 16 + lrow;
                    int boff = dim * 128 + ((ks2 * 64 + lk * 16) ^ ((dim & 7) << 4));
                    bf16x8 vf = *reinterpret_cast<const bf16x8*>((char*)Vt + boff);
                    O[0][ng] = __builtin_amdgcn_mfma_f32_16x16x32_bf16(pa[0], vf, O[0][ng], 0, 0, 0);
                    O[1][ng] = __builtin_amdgcn_mfma_f32_16x16x32_bf16(pa[1], vf, O[1][ng], 0, 0, 0);
                }
            }
        }
        __syncthreads();
    }

    // ---- epilogue: O /= l, store fp32 to CTX [B,S,H*64] ----
#pragma unroll
    for (int mg = 0; mg < 2; ++mg) {
        float inv[4];
#pragma unroll
        for (int j = 0; j < 4; ++j) inv[j] = 1.f / l[mg][j];
#pragma unroll
        for (int ng = 0; ng < 4; ++ng) {
            const int dim = ng * 16 + lrow;
#pragma unroll
            for (int j = 0; j < 4; ++j) {
                int rowabs = wr0 + mg * 16 + lk * 4 + j;
                CTX[((size_t)(b * SEQ + rowabs)) * DMODEL + h * DHEAD + dim]
                    = O[mg][ng][j] * inv[j];
            }
        }
    }
}

// ---------------------------------------------------------------------------
extern "C" void kernel_launch(void* const* d_in, const int* in_sizes, int n_in,
                              void* d_out, int out_size, void* d_ws, size_t ws_size,
                              hipStream_t stream) {
    const float* hs = (const float*)d_in[0];
    const float* Wq = (const float*)d_in[1];
    const float* bq = (const float*)d_in[2];
    const float* Wk = (const float*)d_in[3];
    const float* bk = (const float*)d_in[4];
    const float* Wv = (const float*)d_in[5];
    const float* bv = (const float*)d_in[6];
    const float* Wo = (const float*)d_in[7];
    const float* bo = (const float*)d_in[8];
    float* out = (float*)d_out;

    const size_t NTOK = (size_t)NBATCH * SEQ;        // 4096
    float* ws = (float*)d_ws;
    float* Qf = ws;                                  // fp32 QKV (GEMM outputs)
    float* Kf = ws + 1 * NTOK * DMODEL;
    float* Vf = ws + 2 * NTOK * DMODEL;
    float* Cb = ws + 3 * NTOK * DMODEL;              // attn context fp32
    unsigned short* Qh = (unsigned short*)(ws + 4 * NTOK * DMODEL);  // bf16 [B,H,S,64]
    unsigned short* Kh = Qh + NTOK * DMODEL;
    unsigned short* Vh = Kh + NTOK * DMODEL;         // bf16 [B,H,64,S]
    // total ws use: 64 MB fp32 + 24 MB bf16

    dim3 gg(DMODEL / 128, NTOK / 128);               // (8, 32)
    gemm_bias_kernel<<<gg, 256, 0, stream>>>(hs, Wq, bq, Qf, (int)NTOK, DMODEL, DMODEL);
    gemm_bias_kernel<<<gg, 256, 0, stream>>>(hs, Wk, bk, Kf, (int)NTOK, DMODEL, DMODEL);
    gemm_bias_kernel<<<gg, 256, 0, stream>>>(hs, Wv, bv, Vf, (int)NTOK, DMODEL, DMODEL);

    const int cast_blocks = (int)(NTOK * DMODEL / 4 / 256);   // 4096
    qk_cast_kernel<<<cast_blocks, 256, 0, stream>>>(Qf, Qh, 0.125f);
    qk_cast_kernel<<<cast_blocks, 256, 0, stream>>>(Kf, Kh, 1.0f);
    v_transpose_kernel<<<NBATCH * NHEADS * (SEQ / 64), 256, 0, stream>>>(Vf, Vh);

    attn_mfma_kernel<<<NBATCH * NHEADS * (SEQ / 128), 256, 0, stream>>>(Qh, Kh, Vh, Cb);

    gemm_bias_kernel<<<gg, 256, 0, stream>>>(Cb, Wo, bo, out, (int)NTOK, DMODEL, DMODEL);
}

// Round 3
// 196.851 us; speedup vs baseline: 7.6033x; 3.2356x over previous
//
#include <hip/hip_runtime.h>
#include <math.h>

#define SEQ    2048
#define DMODEL 1024
#define NHEADS 16
#define DHEAD  64
#define NBATCH 2

typedef __attribute__((ext_vector_type(8))) short     bf16x8;
typedef __attribute__((ext_vector_type(4))) float     f32x4;

__device__ __forceinline__ unsigned short f2bf(float f) {
    union { float f; unsigned u; } v; v.f = f;
    unsigned r = (v.u + 0x7FFF + ((v.u >> 16) & 1)) >> 16;
    return (unsigned short)r;
}

// ---------------------------------------------------------------------------
// Cast fp32 -> bf16, flat contiguous. 8 elems/thread.
// ---------------------------------------------------------------------------
__global__ __launch_bounds__(256)
void cast_bf16_kernel(const float* __restrict__ in, unsigned short* __restrict__ out) {
    const size_t g8 = ((size_t)blockIdx.x * 256 + threadIdx.x) * 8;
    float4 a = *reinterpret_cast<const float4*>(in + g8);
    float4 b = *reinterpret_cast<const float4*>(in + g8 + 4);
    bf16x8 o;
    o[0] = (short)f2bf(a.x); o[1] = (short)f2bf(a.y);
    o[2] = (short)f2bf(a.z); o[3] = (short)f2bf(a.w);
    o[4] = (short)f2bf(b.x); o[5] = (short)f2bf(b.y);
    o[6] = (short)f2bf(b.z); o[7] = (short)f2bf(b.w);
    *reinterpret_cast<bf16x8*>(out + g8) = o;
}

// ---------------------------------------------------------------------------
// Transpose-cast a 1024x1024 fp32 weight [K][N] -> bf16 [N][K].
// 64x64 LDS tiles, 256 blocks.
// ---------------------------------------------------------------------------
__global__ __launch_bounds__(256)
void wt_cast_kernel(const float* __restrict__ W, unsigned short* __restrict__ Wt) {
    __shared__ float tile[64][65];
    const int nt  = blockIdx.x & 15;
    const int kt  = blockIdx.x >> 4;
    const int tid = threadIdx.x;

#pragma unroll
    for (int r = 0; r < 4; ++r) {
        int kl = r * 16 + (tid >> 4);
        int nl = (tid & 15) * 4;
        float4 v = *reinterpret_cast<const float4*>(
            &W[(size_t)(kt * 64 + kl) * 1024 + nt * 64 + nl]);
        tile[kl][nl + 0] = v.x; tile[kl][nl + 1] = v.y;
        tile[kl][nl + 2] = v.z; tile[kl][nl + 3] = v.w;
    }
    __syncthreads();

    const int n  = tid >> 2;
    const int kc = (tid & 3) * 16;
    bf16x8 o0, o1;
#pragma unroll
    for (int i = 0; i < 8; ++i) o0[i] = (short)f2bf(tile[kc + i][n]);
#pragma unroll
    for (int i = 0; i < 8; ++i) o1[i] = (short)f2bf(tile[kc + 8 + i][n]);
    unsigned short* op = Wt + (size_t)(nt * 64 + n) * 1024 + kt * 64 + kc;
    *reinterpret_cast<bf16x8*>(op)     = o0;
    *reinterpret_cast<bf16x8*>(op + 8) = o1;
}

// ---------------------------------------------------------------------------
// bf16 MFMA GEMM: C[M,N] = A[M,K] @ Bt[N,K]^T (+bias)
// 128x128 tile, BK=32, 4 waves (2x2), 16x16x32 MFMA, 4x4 frags/wave.
// LDS rows padded to 40 shorts (80 B) -> conflict-free ds_read_b128.
// Reg-staged with next-tile loads issued before compute.
// MODE 0: fused QKV epilogue -> bf16 Q(x0.125)/K head-major [B,H,S,64],
//         V transposed [B,H,64,S]. Which of Q/K/V from bn>>10.
// MODE 1: fp32 C[M,N] + bias.
// ---------------------------------------------------------------------------
template <int MODE>
__global__ __launch_bounds__(256)
void gemm_bf16(const unsigned short* __restrict__ A,
               const unsigned short* __restrict__ Bt,
               const float* __restrict__ bias0, const float* __restrict__ bias1,
               const float* __restrict__ bias2,
               float* __restrict__ Cf,
               unsigned short* __restrict__ Qo, unsigned short* __restrict__ Ko,
               unsigned short* __restrict__ Vo,
               int M, int N, int K) {
    __shared__ unsigned short As[128 * 40];
    __shared__ unsigned short Bs[128 * 40];

    const int tid  = threadIdx.x;
    const int bm   = blockIdx.y * 128;
    const int bn   = blockIdx.x * 128;
    const int w    = tid >> 6;
    const int lane = tid & 63;
    const int lrow = lane & 15;
    const int lk   = lane >> 4;
    const int wm0  = (w >> 1) * 64;
    const int wn0  = (w & 1) * 64;

    const int sr = tid >> 2;          // 0..63
    const int sc = tid & 3;           // 16B chunk

    const unsigned short* Ag = A  + (size_t)bm * K;
    const unsigned short* Bg = Bt + (size_t)bn * K;

    f32x4 acc[4][4];
#pragma unroll
    for (int i = 0; i < 4; ++i)
#pragma unroll
        for (int j = 0; j < 4; ++j) acc[i][j] = (f32x4){0.f, 0.f, 0.f, 0.f};

    bf16x8 ra0, ra1, rb0, rb1;
    {
        const int k = sc * 8;
        ra0 = *reinterpret_cast<const bf16x8*>(Ag + (size_t)sr * K + k);
        ra1 = *reinterpret_cast<const bf16x8*>(Ag + (size_t)(64 + sr) * K + k);
        rb0 = *reinterpret_cast<const bf16x8*>(Bg + (size_t)sr * K + k);
        rb1 = *reinterpret_cast<const bf16x8*>(Bg + (size_t)(64 + sr) * K + k);
    }
    *reinterpret_cast<bf16x8*>(&As[sr * 40 + sc * 8])        = ra0;
    *reinterpret_cast<bf16x8*>(&As[(64 + sr) * 40 + sc * 8]) = ra1;
    *reinterpret_cast<bf16x8*>(&Bs[sr * 40 + sc * 8])        = rb0;
    *reinterpret_cast<bf16x8*>(&Bs[(64 + sr) * 40 + sc * 8]) = rb1;
    __syncthreads();

    const int NT = K / 32;
    for (int kt = 0; kt < NT; ++kt) {
        if (kt + 1 < NT) {
            const int k = (kt + 1) * 32 + sc * 8;
            ra0 = *reinterpret_cast<const bf16x8*>(Ag + (size_t)sr * K + k);
            ra1 = *reinterpret_cast<const bf16x8*>(Ag + (size_t)(64 + sr) * K + k);
            rb0 = *reinterpret_cast<const bf16x8*>(Bg + (size_t)sr * K + k);
            rb1 = *reinterpret_cast<const bf16x8*>(Bg + (size_t)(64 + sr) * K + k);
        }
        bf16x8 af[4], bf[4];
#pragma unroll
        for (int mg = 0; mg < 4; ++mg)
            af[mg] = *reinterpret_cast<const bf16x8*>(
                &As[(wm0 + mg * 16 + lrow) * 40 + lk * 8]);
#pragma unroll
        for (int ng = 0; ng < 4; ++ng)
            bf[ng] = *reinterpret_cast<const bf16x8*>(
                &Bs[(wn0 + ng * 16 + lrow) * 40 + lk * 8]);
#pragma unroll
        for (int mg = 0; mg < 4; ++mg)
#pragma unroll
            for (int ng = 0; ng < 4; ++ng)
                acc[mg][ng] = __builtin_amdgcn_mfma_f32_16x16x32_bf16(
                    af[mg], bf[ng], acc[mg][ng], 0, 0, 0);
        __syncthreads();
        if (kt + 1 < NT) {
            *reinterpret_cast<bf16x8*>(&As[sr * 40 + sc * 8])        = ra0;
            *reinterpret_cast<bf16x8*>(&As[(64 + sr) * 40 + sc * 8]) = ra1;
            *reinterpret_cast<bf16x8*>(&Bs[sr * 40 + sc * 8])        = rb0;
            *reinterpret_cast<bf16x8*>(&Bs[(64 + sr) * 40 + sc * 8]) = rb1;
            __syncthreads();
        }
    }

    if (MODE == 0) {
        const int type = bn >> 10;                 // 0=Q 1=K 2=V
        const int nloc = bn & 1023;
        const float* bias = (type == 0) ? bias0 : (type == 1) ? bias1 : bias2;
#pragma unroll
        for (int ng = 0; ng < 4; ++ng) {
            const int col = nloc + wn0 + ng * 16 + lrow;   // 0..1023
            const float bv = bias[col];
            const int h = col >> 6, d = col & 63;
#pragma unroll
            for (int mg = 0; mg < 4; ++mg) {
#pragma unroll
                for (int j = 0; j < 4; ++j) {
                    const int row = bm + wm0 + mg * 16 + lk * 4 + j;
                    const int b = row >> 11, s = row & 2047;
                    const float val = acc[mg][ng][j] + bv;
                    if (type == 0)
                        Qo[((size_t)(b * 16 + h) * SEQ + s) * 64 + d] = f2bf(val * 0.125f);
                    else if (type == 1)
                        Ko[((size_t)(b * 16 + h) * SEQ + s) * 64 + d] = f2bf(val);
                    else
                        Vo[((size_t)(b * 16 + h) * 64 + d) * SEQ + s] = f2bf(val);
                }
            }
        }
    } else {
#pragma unroll
        for (int ng = 0; ng < 4; ++ng) {
            const int col = bn + wn0 + ng * 16 + lrow;
            const float bv = bias0[col];
#pragma unroll
            for (int mg = 0; mg < 4; ++mg) {
#pragma unroll
                for (int j = 0; j < 4; ++j) {
                    const int row = bm + wm0 + mg * 16 + lk * 4 + j;
                    Cf[(size_t)row * N + col] = acc[mg][ng][j] + bv;
                }
            }
        }
    }
}

// ---------------------------------------------------------------------------
// Causal flash attention with bf16 MFMA (16x16x32), fp32 accumulate.
// Q,K: bf16 [B,H,S,64] (Q pre-scaled by 1/8). Vt: bf16 [B,H,64,S].
// Out CTX: bf16 [B,S,H*64].
// ---------------------------------------------------------------------------
__global__ __launch_bounds__(256)
void attn_mfma_kernel(const unsigned short* __restrict__ Qg,
                      const unsigned short* __restrict__ Kg,
                      const unsigned short* __restrict__ Vtg,
                      unsigned short* __restrict__ CTX) {
    __shared__ __align__(16) unsigned short Ks[64 * 64];
    __shared__ __align__(16) unsigned short Vt[64 * 64];
    __shared__ __align__(16) unsigned short Pl[4][32 * 64];

    const int tiles = SEQ / 128;
    const int bh = blockIdx.x / tiles;
    const int rb = (tiles - 1) - (blockIdx.x % tiles);
    const int b  = bh >> 4;
    const int h  = bh & 15;
    const int r0 = rb * 128;
    const int tid  = threadIdx.x;
    const int w    = tid >> 6;
    const int lane = tid & 63;
    const int lrow = lane & 15;
    const int lk   = lane >> 4;
    const int wr0  = r0 + w * 32;

    const unsigned short* Qb = Qg + ((size_t)bh * SEQ) * DHEAD;
    const unsigned short* Kb = Kg + ((size_t)bh * SEQ) * DHEAD;
    const unsigned short* Vb = Vtg + ((size_t)bh * DHEAD) * SEQ;

    bf16x8 q[2][2];
#pragma unroll
    for (int mg = 0; mg < 2; ++mg)
#pragma unroll
        for (int ks = 0; ks < 2; ++ks)
            q[mg][ks] = *reinterpret_cast<const bf16x8*>(
                Qb + (size_t)(wr0 + mg * 16 + lrow) * DHEAD + ks * 32 + lk * 8);

    f32x4 O[2][4];
    float m[2][4], l[2][4];
#pragma unroll
    for (int mg = 0; mg < 2; ++mg)
#pragma unroll
        for (int j = 0; j < 4; ++j) { m[mg][j] = -1e30f; l[mg][j] = 0.f; }
#pragma unroll
    for (int mg = 0; mg < 2; ++mg)
#pragma unroll
        for (int ng = 0; ng < 4; ++ng) O[mg][ng] = (f32x4){0.f, 0.f, 0.f, 0.f};

    const int ntile = (r0 + 128) / 64;
    for (int t = 0; t < ntile; ++t) {
        const int j0 = t * 64;
        {
            const int row = tid >> 2;
            const int c0  = (tid & 3) * 16;
            const unsigned short* kp = Kb + (size_t)(j0 + row) * DHEAD + c0;
            const unsigned short* vp = Vb + (size_t)row * SEQ + j0 + c0;
#pragma unroll
            for (int u2 = 0; u2 < 2; ++u2) {
                bf16x8 kv = *reinterpret_cast<const bf16x8*>(kp + u2 * 8);
                bf16x8 vv = *reinterpret_cast<const bf16x8*>(vp + u2 * 8);
                int boff = row * 128 + (((c0 + u2 * 8) * 2) ^ ((row & 7) << 4));
                *reinterpret_cast<bf16x8*>((char*)Ks + boff) = kv;
                *reinterpret_cast<bf16x8*>((char*)Vt + boff) = vv;
            }
        }
        __syncthreads();

        if (j0 <= wr0 + 31) {
            f32x4 S[2][4];
#pragma unroll
            for (int mg = 0; mg < 2; ++mg)
#pragma unroll
                for (int kg = 0; kg < 4; ++kg) S[mg][kg] = (f32x4){0.f, 0.f, 0.f, 0.f};
#pragma unroll
            for (int kg = 0; kg < 4; ++kg) {
                const int key = kg * 16 + lrow;
#pragma unroll
                for (int ks = 0; ks < 2; ++ks) {
                    int boff = key * 128 + ((ks * 64 + lk * 16) ^ ((key & 7) << 4));
                    bf16x8 kf = *reinterpret_cast<const bf16x8*>((char*)Ks + boff);
                    S[0][kg] = __builtin_amdgcn_mfma_f32_16x16x32_bf16(q[0][ks], kf, S[0][kg], 0, 0, 0);
                    S[1][kg] = __builtin_amdgcn_mfma_f32_16x16x32_bf16(q[1][ks], kf, S[1][kg], 0, 0, 0);
                }
            }
            if (j0 + 63 > wr0) {
#pragma unroll
                for (int mg = 0; mg < 2; ++mg)
#pragma unroll
                    for (int kg = 0; kg < 4; ++kg) {
                        const int keyabs = j0 + kg * 16 + lrow;
#pragma unroll
                        for (int j = 0; j < 4; ++j) {
                            int rowabs = wr0 + mg * 16 + lk * 4 + j;
                            if (keyabs > rowabs) S[mg][kg][j] = -1e30f;
                        }
                    }
            }
#pragma unroll
            for (int mg = 0; mg < 2; ++mg) {
                float rmax[4], rsum[4], cor[4];
#pragma unroll
                for (int j = 0; j < 4; ++j)
                    rmax[j] = fmaxf(fmaxf(S[mg][0][j], S[mg][1][j]),
                                    fmaxf(S[mg][2][j], S[mg][3][j]));
#pragma unroll
                for (int d = 1; d < 16; d <<= 1)
#pragma unroll
                    for (int j = 0; j < 4; ++j)
                        rmax[j] = fmaxf(rmax[j], __shfl_xor(rmax[j], d));
#pragma unroll
                for (int j = 0; j < 4; ++j) {
                    float mn = fmaxf(m[mg][j], rmax[j]);
                    cor[j] = __expf(m[mg][j] - mn);
                    m[mg][j] = mn;
                    rsum[j] = 0.f;
                }
#pragma unroll
                for (int kg = 0; kg < 4; ++kg)
#pragma unroll
                    for (int j = 0; j < 4; ++j) {
                        float p = __expf(S[mg][kg][j] - m[mg][j]);
                        S[mg][kg][j] = p;
                        rsum[j] += p;
                    }
#pragma unroll
                for (int d = 1; d < 16; d <<= 1)
#pragma unroll
                    for (int j = 0; j < 4; ++j)
                        rsum[j] += __shfl_xor(rsum[j], d);
#pragma unroll
                for (int j = 0; j < 4; ++j)
                    l[mg][j] = l[mg][j] * cor[j] + rsum[j];
#pragma unroll
                for (int ng = 0; ng < 4; ++ng)
#pragma unroll
                    for (int j = 0; j < 4; ++j)
                        O[mg][ng][j] *= cor[j];
#pragma unroll
                for (int kg = 0; kg < 4; ++kg) {
                    const int key = kg * 16 + lrow;
#pragma unroll
                    for (int j = 0; j < 4; ++j) {
                        int rl = mg * 16 + lk * 4 + j;
                        int boff = rl * 128 + ((key * 2) ^ ((rl & 7) << 4));
                        *reinterpret_cast<unsigned short*>((char*)&Pl[w][0] + boff)
                            = f2bf(S[mg][kg][j]);
                    }
                }
            }
            asm volatile("" ::: "memory");
#pragma unroll
            for (int ks2 = 0; ks2 < 2; ++ks2) {
                bf16x8 pa[2];
#pragma unroll
                for (int mg = 0; mg < 2; ++mg) {
                    int rl = mg * 16 + lrow;
                    int boff = rl * 128 + ((ks2 * 64 + lk * 16) ^ ((rl & 7) << 4));
                    pa[mg] = *reinterpret_cast<const bf16x8*>((char*)&Pl[w][0] + boff);
                }
#pragma unroll
                for (int ng = 0; ng < 4; ++ng) {
                    int dim = ng * 16 + lrow;
                    int boff = dim * 128 + ((ks2 * 64 + lk * 16) ^ ((dim & 7) << 4));
                    bf16x8 vf = *reinterpret_cast<const bf16x8*>((char*)Vt + boff);
                    O[0][ng] = __builtin_amdgcn_mfma_f32_16x16x32_bf16(pa[0], vf, O[0][ng], 0, 0, 0);
                    O[1][ng] = __builtin_amdgcn_mfma_f32_16x16x32_bf16(pa[1], vf, O[1][ng], 0, 0, 0);
                }
            }
        }
        __syncthreads();
    }

#pragma unroll
    for (int mg = 0; mg < 2; ++mg) {
        float inv[4];
#pragma unroll
        for (int j = 0; j < 4; ++j) inv[j] = 1.f / l[mg][j];
#pragma unroll
        for (int ng = 0; ng < 4; ++ng) {
            const int dim = ng * 16 + lrow;
#pragma unroll
            for (int j = 0; j < 4; ++j) {
                int rowabs = wr0 + mg * 16 + lk * 4 + j;
                CTX[((size_t)(b * SEQ + rowabs)) * DMODEL + h * DHEAD + dim]
                    = f2bf(O[mg][ng][j] * inv[j]);
            }
        }
    }
}

// ---------------------------------------------------------------------------
extern "C" void kernel_launch(void* const* d_in, const int* in_sizes, int n_in,
                              void* d_out, int out_size, void* d_ws, size_t ws_size,
                              hipStream_t stream) {
    const float* hs = (const float*)d_in[0];
    const float* Wq = (const float*)d_in[1];
    const float* bq = (const float*)d_in[2];
    const float* Wk = (const float*)d_in[3];
    const float* bk = (const float*)d_in[4];
    const float* Wv = (const float*)d_in[5];
    const float* bv = (const float*)d_in[6];
    const float* Wo = (const float*)d_in[7];
    const float* bo = (const float*)d_in[8];
    float* out = (float*)d_out;

    const size_t NTOK = (size_t)NBATCH * SEQ;        // 4096
    unsigned short* hs_bf  = (unsigned short*)d_ws;              // 8 MB
    unsigned short* Wqkv_t = hs_bf + NTOK * DMODEL;              // 6 MB [3072][1024]
    unsigned short* Wo_t   = Wqkv_t + 3072 * 1024;               // 2 MB [1024][1024]
    unsigned short* Qh     = Wo_t + 1024 * 1024;                 // 8 MB [B,H,S,64]
    unsigned short* Kh     = Qh + NTOK * DMODEL;                 // 8 MB
    unsigned short* Vt     = Kh + NTOK * DMODEL;                 // 8 MB [B,H,64,S]
    unsigned short* Cb     = Vt + NTOK * DMODEL;                 // 8 MB ctx bf16

    cast_bf16_kernel<<<(int)(NTOK * DMODEL / 8 / 256), 256, 0, stream>>>(hs, hs_bf);
    wt_cast_kernel<<<256, 256, 0, stream>>>(Wq, Wqkv_t);
    wt_cast_kernel<<<256, 256, 0, stream>>>(Wk, Wqkv_t + 1024 * 1024);
    wt_cast_kernel<<<256, 256, 0, stream>>>(Wv, Wqkv_t + 2 * 1024 * 1024);
    wt_cast_kernel<<<256, 256, 0, stream>>>(Wo, Wo_t);

    dim3 gqkv(3072 / 128, NTOK / 128);               // (24, 32)
    gemm_bf16<0><<<gqkv, 256, 0, stream>>>(hs_bf, Wqkv_t, bq, bk, bv,
                                           nullptr, Qh, Kh, Vt,
                                           (int)NTOK, 3072, DMODEL);

    attn_mfma_kernel<<<NBATCH * NHEADS * (SEQ / 128), 256, 0, stream>>>(Qh, Kh, Vt, Cb);

    dim3 go(DMODEL / 128, NTOK / 128);               // (8, 32)
    gemm_bf16<1><<<go, 256, 0, stream>>>(Cb, Wo_t, bo, nullptr, nullptr,
                                         out, nullptr, nullptr, nullptr,
                                         (int)NTOK, DMODEL, DMODEL);
}

// Round 4
// 149.521 us; speedup vs baseline: 10.0101x; 1.3165x over previous
//
#include <hip/hip_runtime.h>
#include <math.h>

#define SEQ    2048
#define DMODEL 1024
#define NHEADS 16
#define DHEAD  64
#define NBATCH 2

typedef __attribute__((ext_vector_type(8)))  short bf16x8;
typedef __attribute__((ext_vector_type(4)))  float f32x4;
typedef __attribute__((ext_vector_type(16))) float f32x16;

__device__ __forceinline__ unsigned short f2bf(float f) {
    union { float f; unsigned u; } v; v.f = f;
    unsigned r = (v.u + 0x7FFF + ((v.u >> 16) & 1)) >> 16;
    return (unsigned short)r;
}

__device__ __forceinline__ unsigned cvt_pk_bf16(float lo, float hi) {
    unsigned r;
    asm("v_cvt_pk_bf16_f32 %0, %1, %2" : "=v"(r) : "v"(lo), "v"(hi));
    return r;
}

// ---------------------------------------------------------------------------
// Cast fp32 -> bf16, flat contiguous. 8 elems/thread.
// ---------------------------------------------------------------------------
__global__ __launch_bounds__(256)
void cast_bf16_kernel(const float* __restrict__ in, unsigned short* __restrict__ out) {
    const size_t g8 = ((size_t)blockIdx.x * 256 + threadIdx.x) * 8;
    float4 a = *reinterpret_cast<const float4*>(in + g8);
    float4 b = *reinterpret_cast<const float4*>(in + g8 + 4);
    bf16x8 o;
    o[0] = (short)f2bf(a.x); o[1] = (short)f2bf(a.y);
    o[2] = (short)f2bf(a.z); o[3] = (short)f2bf(a.w);
    o[4] = (short)f2bf(b.x); o[5] = (short)f2bf(b.y);
    o[6] = (short)f2bf(b.z); o[7] = (short)f2bf(b.w);
    *reinterpret_cast<bf16x8*>(out + g8) = o;
}

// ---------------------------------------------------------------------------
// Transpose-cast a 1024x1024 fp32 weight [K][N] -> bf16 [N][K].
// ---------------------------------------------------------------------------
__global__ __launch_bounds__(256)
void wt_cast_kernel(const float* __restrict__ W, unsigned short* __restrict__ Wt) {
    __shared__ float tile[64][65];
    const int nt  = blockIdx.x & 15;
    const int kt  = blockIdx.x >> 4;
    const int tid = threadIdx.x;

#pragma unroll
    for (int r = 0; r < 4; ++r) {
        int kl = r * 16 + (tid >> 4);
        int nl = (tid & 15) * 4;
        float4 v = *reinterpret_cast<const float4*>(
            &W[(size_t)(kt * 64 + kl) * 1024 + nt * 64 + nl]);
        tile[kl][nl + 0] = v.x; tile[kl][nl + 1] = v.y;
        tile[kl][nl + 2] = v.z; tile[kl][nl + 3] = v.w;
    }
    __syncthreads();

    const int n  = tid >> 2;
    const int kc = (tid & 3) * 16;
    bf16x8 o0, o1;
#pragma unroll
    for (int i = 0; i < 8; ++i) o0[i] = (short)f2bf(tile[kc + i][n]);
#pragma unroll
    for (int i = 0; i < 8; ++i) o1[i] = (short)f2bf(tile[kc + 8 + i][n]);
    unsigned short* op = Wt + (size_t)(nt * 64 + n) * 1024 + kt * 64 + kc;
    *reinterpret_cast<bf16x8*>(op)     = o0;
    *reinterpret_cast<bf16x8*>(op + 8) = o1;
}

// ---------------------------------------------------------------------------
// bf16 MFMA GEMM (unchanged from R3): C = A @ Bt^T (+bias)
// ---------------------------------------------------------------------------
template <int MODE>
__global__ __launch_bounds__(256)
void gemm_bf16(const unsigned short* __restrict__ A,
               const unsigned short* __restrict__ Bt,
               const float* __restrict__ bias0, const float* __restrict__ bias1,
               const float* __restrict__ bias2,
               float* __restrict__ Cf,
               unsigned short* __restrict__ Qo, unsigned short* __restrict__ Ko,
               unsigned short* __restrict__ Vo,
               int M, int N, int K) {
    __shared__ unsigned short As[128 * 40];
    __shared__ unsigned short Bs[128 * 40];

    const int tid  = threadIdx.x;
    const int bm   = blockIdx.y * 128;
    const int bn   = blockIdx.x * 128;
    const int w    = tid >> 6;
    const int lane = tid & 63;
    const int lrow = lane & 15;
    const int lk   = lane >> 4;
    const int wm0  = (w >> 1) * 64;
    const int wn0  = (w & 1) * 64;

    const int sr = tid >> 2;
    const int sc = tid & 3;

    const unsigned short* Ag = A  + (size_t)bm * K;
    const unsigned short* Bg = Bt + (size_t)bn * K;

    f32x4 acc[4][4];
#pragma unroll
    for (int i = 0; i < 4; ++i)
#pragma unroll
        for (int j = 0; j < 4; ++j) acc[i][j] = (f32x4){0.f, 0.f, 0.f, 0.f};

    bf16x8 ra0, ra1, rb0, rb1;
    {
        const int k = sc * 8;
        ra0 = *reinterpret_cast<const bf16x8*>(Ag + (size_t)sr * K + k);
        ra1 = *reinterpret_cast<const bf16x8*>(Ag + (size_t)(64 + sr) * K + k);
        rb0 = *reinterpret_cast<const bf16x8*>(Bg + (size_t)sr * K + k);
        rb1 = *reinterpret_cast<const bf16x8*>(Bg + (size_t)(64 + sr) * K + k);
    }
    *reinterpret_cast<bf16x8*>(&As[sr * 40 + sc * 8])        = ra0;
    *reinterpret_cast<bf16x8*>(&As[(64 + sr) * 40 + sc * 8]) = ra1;
    *reinterpret_cast<bf16x8*>(&Bs[sr * 40 + sc * 8])        = rb0;
    *reinterpret_cast<bf16x8*>(&Bs[(64 + sr) * 40 + sc * 8]) = rb1;
    __syncthreads();

    const int NT = K / 32;
    for (int kt = 0; kt < NT; ++kt) {
        if (kt + 1 < NT) {
            const int k = (kt + 1) * 32 + sc * 8;
            ra0 = *reinterpret_cast<const bf16x8*>(Ag + (size_t)sr * K + k);
            ra1 = *reinterpret_cast<const bf16x8*>(Ag + (size_t)(64 + sr) * K + k);
            rb0 = *reinterpret_cast<const bf16x8*>(Bg + (size_t)sr * K + k);
            rb1 = *reinterpret_cast<const bf16x8*>(Bg + (size_t)(64 + sr) * K + k);
        }
        bf16x8 af[4], bf[4];
#pragma unroll
        for (int mg = 0; mg < 4; ++mg)
            af[mg] = *reinterpret_cast<const bf16x8*>(
                &As[(wm0 + mg * 16 + lrow) * 40 + lk * 8]);
#pragma unroll
        for (int ng = 0; ng < 4; ++ng)
            bf[ng] = *reinterpret_cast<const bf16x8*>(
                &Bs[(wn0 + ng * 16 + lrow) * 40 + lk * 8]);
#pragma unroll
        for (int mg = 0; mg < 4; ++mg)
#pragma unroll
            for (int ng = 0; ng < 4; ++ng)
                acc[mg][ng] = __builtin_amdgcn_mfma_f32_16x16x32_bf16(
                    af[mg], bf[ng], acc[mg][ng], 0, 0, 0);
        __syncthreads();
        if (kt + 1 < NT) {
            *reinterpret_cast<bf16x8*>(&As[sr * 40 + sc * 8])        = ra0;
            *reinterpret_cast<bf16x8*>(&As[(64 + sr) * 40 + sc * 8]) = ra1;
            *reinterpret_cast<bf16x8*>(&Bs[sr * 40 + sc * 8])        = rb0;
            *reinterpret_cast<bf16x8*>(&Bs[(64 + sr) * 40 + sc * 8]) = rb1;
            __syncthreads();
        }
    }

    if (MODE == 0) {
        const int type = bn >> 10;                 // 0=Q 1=K 2=V
        const int nloc = bn & 1023;
        const float* bias = (type == 0) ? bias0 : (type == 1) ? bias1 : bias2;
#pragma unroll
        for (int ng = 0; ng < 4; ++ng) {
            const int col = nloc + wn0 + ng * 16 + lrow;
            const float bv = bias[col];
            const int h = col >> 6, d = col & 63;
#pragma unroll
            for (int mg = 0; mg < 4; ++mg) {
#pragma unroll
                for (int j = 0; j < 4; ++j) {
                    const int row = bm + wm0 + mg * 16 + lk * 4 + j;
                    const int b = row >> 11, s = row & 2047;
                    const float val = acc[mg][ng][j] + bv;
                    if (type == 0)
                        Qo[((size_t)(b * 16 + h) * SEQ + s) * 64 + d] = f2bf(val * 0.125f);
                    else if (type == 1)
                        Ko[((size_t)(b * 16 + h) * SEQ + s) * 64 + d] = f2bf(val);
                    else
                        Vo[((size_t)(b * 16 + h) * 64 + d) * SEQ + s] = f2bf(val);
                }
            }
        }
    } else {
#pragma unroll
        for (int ng = 0; ng < 4; ++ng) {
            const int col = bn + wn0 + ng * 16 + lrow;
            const float bv = bias0[col];
#pragma unroll
            for (int mg = 0; mg < 4; ++mg) {
#pragma unroll
                for (int j = 0; j < 4; ++j) {
                    const int row = bm + wm0 + mg * 16 + lk * 4 + j;
                    Cf[(size_t)row * N + col] = acc[mg][ng][j] + bv;
                }
            }
        }
    }
}

// ---------------------------------------------------------------------------
// Causal flash attention, swapped-operand 32x32x16 MFMA (m214 structure).
// Q,K: bf16 [B,H,S,64] (Q pre-scaled by 1/8). Vt: bf16 [B,H,64,S].
// Out CTX: bf16 [B,S,H*64].
// Per wave: 32 q-rows. S^T = mfma(K,Q): lane holds P-row (32 keys split
// across lane-pair l/l+32) for q-row col=lane&31 -> softmax in-register,
// 1 shfl per tile. PV: O^T = mfma(V^T, P^T); P^T fragments built with
// cvt_pk_bf16 + v_permlane32_swap (no LDS round-trip).
// ---------------------------------------------------------------------------
__global__ __launch_bounds__(256)
void attn_mfma_kernel(const unsigned short* __restrict__ Qg,
                      const unsigned short* __restrict__ Kg,
                      const unsigned short* __restrict__ Vtg,
                      unsigned short* __restrict__ CTX) {
    __shared__ __align__(16) unsigned short Ks[64 * 64];   // [key][dim], swizzled
    __shared__ __align__(16) unsigned short Vt[64 * 64];   // [dim][key], swizzled

    const int tiles = SEQ / 128;                  // 16
    const int bh = blockIdx.x / tiles;
    const int rb = (tiles - 1) - (blockIdx.x % tiles);   // big blocks first
    const int b  = bh >> 4;
    const int h  = bh & 15;
    const int r0 = rb * 128;
    const int tid  = threadIdx.x;
    const int w    = tid >> 6;
    const int lane = tid & 63;
    const int qcol = lane & 31;                   // q-row local (C col / A row)
    const int hlf  = lane >> 5;
    const int wr0  = r0 + w * 32;
    const int qrow = wr0 + qcol;                  // absolute q row

    const unsigned short* Kb = Kg + ((size_t)bh * SEQ) * DHEAD;
    const unsigned short* Vb = Vtg + ((size_t)bh * DHEAD) * SEQ;

    // Q fragment (B-operand): col=qrow, k = ksub*16 + hlf*8 + i
    bf16x8 qf[4];
    {
        const unsigned short* qp = Qg + ((size_t)bh * SEQ + qrow) * DHEAD + hlf * 8;
#pragma unroll
        for (int ksub = 0; ksub < 4; ++ksub)
            qf[ksub] = *reinterpret_cast<const bf16x8*>(qp + ksub * 16);
    }

    f32x16 O0, O1;            // O^T: col=qrow, rows = dims db*32+(r&3)+8*(r>>2)+4*hlf
#pragma unroll
    for (int r = 0; r < 16; ++r) { O0[r] = 0.f; O1[r] = 0.f; }
    float m = -1e30f, l = 0.f;

    const int ntile = (r0 + 128) / 64;
    for (int t = 0; t < ntile; ++t) {
        const int j0 = t * 64;
        // ---- stage K tile [key][dim] and Vt tile [dim][key], swizzled ----
        {
            const int row = tid >> 2;
            const int c0  = (tid & 3) * 16;
            const unsigned short* kp = Kb + (size_t)(j0 + row) * DHEAD + c0;
            const unsigned short* vp = Vb + (size_t)row * SEQ + j0 + c0;
#pragma unroll
            for (int u2 = 0; u2 < 2; ++u2) {
                bf16x8 kv = *reinterpret_cast<const bf16x8*>(kp + u2 * 8);
                bf16x8 vv = *reinterpret_cast<const bf16x8*>(vp + u2 * 8);
                int boff = row * 128 + (((c0 + u2 * 8) * 2) ^ ((row & 7) << 4));
                *reinterpret_cast<bf16x8*>((char*)Ks + boff) = kv;
                *reinterpret_cast<bf16x8*>((char*)Vt + boff) = vv;
            }
        }
        __syncthreads();

        if (j0 <= wr0 + 31) {
            // ---- S^T = K * Q^T : S[kb] covers keys kb*32..+31 ----
            f32x16 S[2];
#pragma unroll
            for (int r = 0; r < 16; ++r) { S[0][r] = 0.f; S[1][r] = 0.f; }
#pragma unroll
            for (int kb = 0; kb < 2; ++kb) {
                const int key = kb * 32 + qcol;   // A-frag row
#pragma unroll
                for (int ksub = 0; ksub < 4; ++ksub) {
                    int boff = key * 128 + ((ksub * 32 + hlf * 16) ^ ((key & 7) << 4));
                    bf16x8 kf = *reinterpret_cast<const bf16x8*>((char*)Ks + boff);
                    S[kb] = __builtin_amdgcn_mfma_f32_32x32x16_bf16(
                        kf, qf[ksub], S[kb], 0, 0, 0);
                }
            }

            // ---- causal mask (boundary tiles only) ----
            if (j0 + 63 > wr0) {
#pragma unroll
                for (int kb = 0; kb < 2; ++kb)
#pragma unroll
                    for (int r = 0; r < 16; ++r) {
                        int ka = j0 + kb * 32 + (r & 3) + 8 * (r >> 2) + 4 * hlf;
                        if (ka > qrow) S[kb][r] = -1e30f;
                    }
            }

            // ---- softmax: in-register row reduce + 1 shfl ----
            float pm = S[0][0];
#pragma unroll
            for (int r = 1; r < 16; ++r) pm = fmaxf(pm, S[0][r]);
#pragma unroll
            for (int r = 0; r < 16; ++r) pm = fmaxf(pm, S[1][r]);
            pm = fmaxf(pm, __shfl_xor(pm, 32));

            if (__any(pm > m)) {                 // exact defer-rescale
                float mnew = fmaxf(m, pm);
                float cor  = __expf(m - mnew);
                m = mnew;
                l *= cor;
#pragma unroll
                for (int r = 0; r < 16; ++r) { O0[r] *= cor; O1[r] *= cor; }
            }

            float ls = 0.f;
#pragma unroll
            for (int kb = 0; kb < 2; ++kb)
#pragma unroll
                for (int r = 0; r < 16; ++r) {
                    float p = __expf(S[kb][r] - m);
                    S[kb][r] = p;
                    ls += p;
                }
            l += ls;

            // ---- PV: O^T += V^T * P^T, P^T frags via cvt_pk + permlane swap ----
#pragma unroll
            for (int kc = 0; kc < 4; ++kc) {
                const int kb = kc >> 1;
                const int R0 = (kc & 1) * 8;
                unsigned pa = cvt_pk_bf16(S[kb][R0 + 0], S[kb][R0 + 1]);
                unsigned pc = cvt_pk_bf16(S[kb][R0 + 4], S[kb][R0 + 5]);
                asm("v_permlane32_swap_b32 %0, %1" : "+v"(pa), "+v"(pc));
                unsigned pb = cvt_pk_bf16(S[kb][R0 + 2], S[kb][R0 + 3]);
                unsigned pd = cvt_pk_bf16(S[kb][R0 + 6], S[kb][R0 + 7]);
                asm("v_permlane32_swap_b32 %0, %1" : "+v"(pb), "+v"(pd));
                union { unsigned u[4]; bf16x8 v; } pf;
                pf.u[0] = pa; pf.u[1] = pb; pf.u[2] = pc; pf.u[3] = pd;
#pragma unroll
                for (int db = 0; db < 2; ++db) {
                    const int dim = db * 32 + qcol;   // A-frag row (V^T)
                    int boff = dim * 128 + ((kc * 32 + hlf * 16) ^ ((dim & 7) << 4));
                    bf16x8 vf = *reinterpret_cast<const bf16x8*>((char*)Vt + boff);
                    if (db == 0)
                        O0 = __builtin_amdgcn_mfma_f32_32x32x16_bf16(vf, pf.v, O0, 0, 0, 0);
                    else
                        O1 = __builtin_amdgcn_mfma_f32_32x32x16_bf16(vf, pf.v, O1, 0, 0, 0);
                }
            }
        }
        __syncthreads();
    }

    // ---- epilogue: combine lane-pair l, O/l, pack bf16, store ----
    l += __shfl_xor(l, 32);
    const float inv = 1.f / l;
    unsigned short* crow = CTX + ((size_t)(b * SEQ + qrow)) * DMODEL + h * DHEAD;
#pragma unroll
    for (int pq = 0; pq < 4; ++pq) {
        unsigned w0 = cvt_pk_bf16(O0[pq * 4 + 0] * inv, O0[pq * 4 + 1] * inv);
        unsigned w1 = cvt_pk_bf16(O0[pq * 4 + 2] * inv, O0[pq * 4 + 3] * inv);
        uint2 val; val.x = w0; val.y = w1;
        *reinterpret_cast<uint2*>(crow + 8 * pq + 4 * hlf) = val;
    }
#pragma unroll
    for (int pq = 0; pq < 4; ++pq) {
        unsigned w0 = cvt_pk_bf16(O1[pq * 4 + 0] * inv, O1[pq * 4 + 1] * inv);
        unsigned w1 = cvt_pk_bf16(O1[pq * 4 + 2] * inv, O1[pq * 4 + 3] * inv);
        uint2 val; val.x = w0; val.y = w1;
        *reinterpret_cast<uint2*>(crow + 32 + 8 * pq + 4 * hlf) = val;
    }
}

// ---------------------------------------------------------------------------
extern "C" void kernel_launch(void* const* d_in, const int* in_sizes, int n_in,
                              void* d_out, int out_size, void* d_ws, size_t ws_size,
                              hipStream_t stream) {
    const float* hs = (const float*)d_in[0];
    const float* Wq = (const float*)d_in[1];
    const float* bq = (const float*)d_in[2];
    const float* Wk = (const float*)d_in[3];
    const float* bk = (const float*)d_in[4];
    const float* Wv = (const float*)d_in[5];
    const float* bv = (const float*)d_in[6];
    const float* Wo = (const float*)d_in[7];
    const float* bo = (const float*)d_in[8];
    float* out = (float*)d_out;

    const size_t NTOK = (size_t)NBATCH * SEQ;        // 4096
    unsigned short* hs_bf  = (unsigned short*)d_ws;              // 8 MB
    unsigned short* Wqkv_t = hs_bf + NTOK * DMODEL;              // 6 MB [3072][1024]
    unsigned short* Wo_t   = Wqkv_t + 3072 * 1024;               // 2 MB [1024][1024]
    unsigned short* Qh     = Wo_t + 1024 * 1024;                 // 8 MB [B,H,S,64]
    unsigned short* Kh     = Qh + NTOK * DMODEL;                 // 8 MB
    unsigned short* Vt     = Kh + NTOK * DMODEL;                 // 8 MB [B,H,64,S]
    unsigned short* Cb     = Vt + NTOK * DMODEL;                 // 8 MB ctx bf16

    cast_bf16_kernel<<<(int)(NTOK * DMODEL / 8 / 256), 256, 0, stream>>>(hs, hs_bf);
    wt_cast_kernel<<<256, 256, 0, stream>>>(Wq, Wqkv_t);
    wt_cast_kernel<<<256, 256, 0, stream>>>(Wk, Wqkv_t + 1024 * 1024);
    wt_cast_kernel<<<256, 256, 0, stream>>>(Wv, Wqkv_t + 2 * 1024 * 1024);
    wt_cast_kernel<<<256, 256, 0, stream>>>(Wo, Wo_t);

    dim3 gqkv(3072 / 128, NTOK / 128);               // (24, 32)
    gemm_bf16<0><<<gqkv, 256, 0, stream>>>(hs_bf, Wqkv_t, bq, bk, bv,
                                           nullptr, Qh, Kh, Vt,
                                           (int)NTOK, 3072, DMODEL);

    attn_mfma_kernel<<<NBATCH * NHEADS * (SEQ / 128), 256, 0, stream>>>(Qh, Kh, Vt, Cb);

    dim3 go(DMODEL / 128, NTOK / 128);               // (8, 32)
    gemm_bf16<1><<<go, 256, 0, stream>>>(Cb, Wo_t, bo, nullptr, nullptr,
                                         out, nullptr, nullptr, nullptr,
                                         (int)NTOK, DMODEL, DMODEL);
}

// Round 5
// 135.854 us; speedup vs baseline: 11.0172x; 1.1006x over previous
//
#include <hip/hip_runtime.h>
#include <math.h>

#define SEQ    2048
#define DMODEL 1024
#define NHEADS 16
#define DHEAD  64
#define NBATCH 2

typedef __attribute__((ext_vector_type(8)))  short bf16x8;
typedef __attribute__((ext_vector_type(4)))  float f32x4;
typedef __attribute__((ext_vector_type(16))) float f32x16;

__device__ __forceinline__ unsigned short f2bf(float f) {
    union { float f; unsigned u; } v; v.f = f;
    unsigned r = (v.u + 0x7FFF + ((v.u >> 16) & 1)) >> 16;
    return (unsigned short)r;
}

__device__ __forceinline__ unsigned cvt_pk_bf16(float lo, float hi) {
    unsigned r;
    asm("v_cvt_pk_bf16_f32 %0, %1, %2" : "=v"(r) : "v"(lo), "v"(hi));
    return r;
}

// ---------------------------------------------------------------------------
// Cast fp32 -> bf16, flat contiguous. 8 elems/thread.
// ---------------------------------------------------------------------------
__global__ __launch_bounds__(256)
void cast_bf16_kernel(const float* __restrict__ in, unsigned short* __restrict__ out) {
    const size_t g8 = ((size_t)blockIdx.x * 256 + threadIdx.x) * 8;
    float4 a = *reinterpret_cast<const float4*>(in + g8);
    float4 b = *reinterpret_cast<const float4*>(in + g8 + 4);
    bf16x8 o;
    o[0] = (short)f2bf(a.x); o[1] = (short)f2bf(a.y);
    o[2] = (short)f2bf(a.z); o[3] = (short)f2bf(a.w);
    o[4] = (short)f2bf(b.x); o[5] = (short)f2bf(b.y);
    o[6] = (short)f2bf(b.z); o[7] = (short)f2bf(b.w);
    *reinterpret_cast<bf16x8*>(out + g8) = o;
}

// ---------------------------------------------------------------------------
// Transpose-cast a 1024x1024 fp32 weight [K][N] -> bf16 [N][K].
// ---------------------------------------------------------------------------
__global__ __launch_bounds__(256)
void wt_cast_kernel(const float* __restrict__ W, unsigned short* __restrict__ Wt) {
    __shared__ float tile[64][65];
    const int nt  = blockIdx.x & 15;
    const int kt  = blockIdx.x >> 4;
    const int tid = threadIdx.x;

#pragma unroll
    for (int r = 0; r < 4; ++r) {
        int kl = r * 16 + (tid >> 4);
        int nl = (tid & 15) * 4;
        float4 v = *reinterpret_cast<const float4*>(
            &W[(size_t)(kt * 64 + kl) * 1024 + nt * 64 + nl]);
        tile[kl][nl + 0] = v.x; tile[kl][nl + 1] = v.y;
        tile[kl][nl + 2] = v.z; tile[kl][nl + 3] = v.w;
    }
    __syncthreads();

    const int n  = tid >> 2;
    const int kc = (tid & 3) * 16;
    bf16x8 o0, o1;
#pragma unroll
    for (int i = 0; i < 8; ++i) o0[i] = (short)f2bf(tile[kc + i][n]);
#pragma unroll
    for (int i = 0; i < 8; ++i) o1[i] = (short)f2bf(tile[kc + 8 + i][n]);
    unsigned short* op = Wt + (size_t)(nt * 64 + n) * 1024 + kt * 64 + kc;
    *reinterpret_cast<bf16x8*>(op)     = o0;
    *reinterpret_cast<bf16x8*>(op + 8) = o1;
}

// ---------------------------------------------------------------------------
// bf16 MFMA GEMM: C = A @ Bt^T (+bias)
// MODE 0 fused QKV epilogue (Q scale now folds log2(e) for exp2 softmax).
// ---------------------------------------------------------------------------
template <int MODE>
__global__ __launch_bounds__(256)
void gemm_bf16(const unsigned short* __restrict__ A,
               const unsigned short* __restrict__ Bt,
               const float* __restrict__ bias0, const float* __restrict__ bias1,
               const float* __restrict__ bias2,
               float* __restrict__ Cf,
               unsigned short* __restrict__ Qo, unsigned short* __restrict__ Ko,
               unsigned short* __restrict__ Vo,
               int M, int N, int K) {
    __shared__ unsigned short As[128 * 40];
    __shared__ unsigned short Bs[128 * 40];

    const int tid  = threadIdx.x;
    const int bm   = blockIdx.y * 128;
    const int bn   = blockIdx.x * 128;
    const int w    = tid >> 6;
    const int lane = tid & 63;
    const int lrow = lane & 15;
    const int lk   = lane >> 4;
    const int wm0  = (w >> 1) * 64;
    const int wn0  = (w & 1) * 64;

    const int sr = tid >> 2;
    const int sc = tid & 3;

    const unsigned short* Ag = A  + (size_t)bm * K;
    const unsigned short* Bg = Bt + (size_t)bn * K;

    f32x4 acc[4][4];
#pragma unroll
    for (int i = 0; i < 4; ++i)
#pragma unroll
        for (int j = 0; j < 4; ++j) acc[i][j] = (f32x4){0.f, 0.f, 0.f, 0.f};

    bf16x8 ra0, ra1, rb0, rb1;
    {
        const int k = sc * 8;
        ra0 = *reinterpret_cast<const bf16x8*>(Ag + (size_t)sr * K + k);
        ra1 = *reinterpret_cast<const bf16x8*>(Ag + (size_t)(64 + sr) * K + k);
        rb0 = *reinterpret_cast<const bf16x8*>(Bg + (size_t)sr * K + k);
        rb1 = *reinterpret_cast<const bf16x8*>(Bg + (size_t)(64 + sr) * K + k);
    }
    *reinterpret_cast<bf16x8*>(&As[sr * 40 + sc * 8])        = ra0;
    *reinterpret_cast<bf16x8*>(&As[(64 + sr) * 40 + sc * 8]) = ra1;
    *reinterpret_cast<bf16x8*>(&Bs[sr * 40 + sc * 8])        = rb0;
    *reinterpret_cast<bf16x8*>(&Bs[(64 + sr) * 40 + sc * 8]) = rb1;
    __syncthreads();

    const int NT = K / 32;
    for (int kt = 0; kt < NT; ++kt) {
        if (kt + 1 < NT) {
            const int k = (kt + 1) * 32 + sc * 8;
            ra0 = *reinterpret_cast<const bf16x8*>(Ag + (size_t)sr * K + k);
            ra1 = *reinterpret_cast<const bf16x8*>(Ag + (size_t)(64 + sr) * K + k);
            rb0 = *reinterpret_cast<const bf16x8*>(Bg + (size_t)sr * K + k);
            rb1 = *reinterpret_cast<const bf16x8*>(Bg + (size_t)(64 + sr) * K + k);
        }
        bf16x8 af[4], bf[4];
#pragma unroll
        for (int mg = 0; mg < 4; ++mg)
            af[mg] = *reinterpret_cast<const bf16x8*>(
                &As[(wm0 + mg * 16 + lrow) * 40 + lk * 8]);
#pragma unroll
        for (int ng = 0; ng < 4; ++ng)
            bf[ng] = *reinterpret_cast<const bf16x8*>(
                &Bs[(wn0 + ng * 16 + lrow) * 40 + lk * 8]);
#pragma unroll
        for (int mg = 0; mg < 4; ++mg)
#pragma unroll
            for (int ng = 0; ng < 4; ++ng)
                acc[mg][ng] = __builtin_amdgcn_mfma_f32_16x16x32_bf16(
                    af[mg], bf[ng], acc[mg][ng], 0, 0, 0);
        __syncthreads();
        if (kt + 1 < NT) {
            *reinterpret_cast<bf16x8*>(&As[sr * 40 + sc * 8])        = ra0;
            *reinterpret_cast<bf16x8*>(&As[(64 + sr) * 40 + sc * 8]) = ra1;
            *reinterpret_cast<bf16x8*>(&Bs[sr * 40 + sc * 8])        = rb0;
            *reinterpret_cast<bf16x8*>(&Bs[(64 + sr) * 40 + sc * 8]) = rb1;
            __syncthreads();
        }
    }

    if (MODE == 0) {
        const int type = bn >> 10;                 // 0=Q 1=K 2=V
        const int nloc = bn & 1023;
        const float* bias = (type == 0) ? bias0 : (type == 1) ? bias1 : bias2;
        // Q scale: 1/8 (1/sqrt(Dh)) * log2(e)  -> softmax runs in exp2 domain
        const float QSCALE = 0.125f * 1.44269504088896f;
#pragma unroll
        for (int ng = 0; ng < 4; ++ng) {
            const int col = nloc + wn0 + ng * 16 + lrow;
            const float bv = bias[col];
            const int h = col >> 6, d = col & 63;
#pragma unroll
            for (int mg = 0; mg < 4; ++mg) {
#pragma unroll
                for (int j = 0; j < 4; ++j) {
                    const int row = bm + wm0 + mg * 16 + lk * 4 + j;
                    const int b = row >> 11, s = row & 2047;
                    const float val = acc[mg][ng][j] + bv;
                    if (type == 0)
                        Qo[((size_t)(b * 16 + h) * SEQ + s) * 64 + d] = f2bf(val * QSCALE);
                    else if (type == 1)
                        Ko[((size_t)(b * 16 + h) * SEQ + s) * 64 + d] = f2bf(val);
                    else
                        Vo[((size_t)(b * 16 + h) * 64 + d) * SEQ + s] = f2bf(val);
                }
            }
        }
    } else {
#pragma unroll
        for (int ng = 0; ng < 4; ++ng) {
            const int col = bn + wn0 + ng * 16 + lrow;
            const float bv = bias0[col];
#pragma unroll
            for (int mg = 0; mg < 4; ++mg) {
#pragma unroll
                for (int j = 0; j < 4; ++j) {
                    const int row = bm + wm0 + mg * 16 + lk * 4 + j;
                    Cf[(size_t)row * N + col] = acc[mg][ng][j] + bv;
                }
            }
        }
    }
}

// ---------------------------------------------------------------------------
// Causal flash attention, swapped-operand 32x32x16 MFMA.
// R5: double-buffered LDS + async-STAGE split (prefetch issued after the
// barrier, drains only at the NEXT barrier -> latency hidden under compute),
// 1 barrier/tile, exp2-domain softmax, setprio around MFMA clusters,
// pairing swizzle for tail balance.
// ---------------------------------------------------------------------------
__global__ __launch_bounds__(256)
void attn_mfma_kernel(const unsigned short* __restrict__ Qg,
                      const unsigned short* __restrict__ Kg,
                      const unsigned short* __restrict__ Vtg,
                      unsigned short* __restrict__ CTX) {
    __shared__ __align__(16) unsigned short Ks[2][64 * 64];   // [buf][key][dim] swz
    __shared__ __align__(16) unsigned short Vt[2][64 * 64];   // [buf][dim][key] swz

    const int bid = blockIdx.x;
    const int bh  = bid >> 4;                     // 0..31
    const int pos = bid & 15;
    // alternate big-first/small-first so co-dispatched pairs balance
    const int dir = ((bid >> 4) ^ (bid >> 8)) & 1;
    const int rb  = dir ? pos : (15 - pos);
    const int b  = bh >> 4;
    const int h  = bh & 15;
    const int r0 = rb * 128;
    const int tid  = threadIdx.x;
    const int w    = tid >> 6;
    const int lane = tid & 63;
    const int qcol = lane & 31;
    const int hlf  = lane >> 5;
    const int wr0  = r0 + w * 32;
    const int qrow = wr0 + qcol;

    const unsigned short* Kb = Kg + ((size_t)bh * SEQ) * DHEAD;
    const unsigned short* Vb = Vtg + ((size_t)bh * DHEAD) * SEQ;

    // Q fragment (B-operand)
    bf16x8 qf[4];
    {
        const unsigned short* qp = Qg + ((size_t)bh * SEQ + qrow) * DHEAD + hlf * 8;
#pragma unroll
        for (int ksub = 0; ksub < 4; ++ksub)
            qf[ksub] = *reinterpret_cast<const bf16x8*>(qp + ksub * 16);
    }

    f32x16 O0, O1;
#pragma unroll
    for (int r = 0; r < 16; ++r) { O0[r] = 0.f; O1[r] = 0.f; }
    float m = -1e30f, l = 0.f;

    const int srow = tid >> 2;           // 0..63
    const int c0   = (tid & 3) * 16;     // shorts
    const int sb0  = srow * 128 + ((c0 * 2) ^ ((srow & 7) << 4));
    const int sb1  = srow * 128 + (((c0 + 8) * 2) ^ ((srow & 7) << 4));

    // prologue: load tile 0 into regs
    bf16x8 rk0, rk1, rv0, rv1;
    {
        const unsigned short* kp = Kb + (size_t)srow * DHEAD + c0;
        const unsigned short* vp = Vb + (size_t)srow * SEQ + c0;
        rk0 = *reinterpret_cast<const bf16x8*>(kp);
        rk1 = *reinterpret_cast<const bf16x8*>(kp + 8);
        rv0 = *reinterpret_cast<const bf16x8*>(vp);
        rv1 = *reinterpret_cast<const bf16x8*>(vp + 8);
    }

    const int ntile = (r0 + 128) / 64;
    for (int t = 0; t < ntile; ++t) {
        const int j0 = t * 64;
        const int buf = t & 1;
        // ---- commit staged regs to LDS[buf] ----
        *reinterpret_cast<bf16x8*>((char*)&Ks[buf][0] + sb0) = rk0;
        *reinterpret_cast<bf16x8*>((char*)&Ks[buf][0] + sb1) = rk1;
        *reinterpret_cast<bf16x8*>((char*)&Vt[buf][0] + sb0) = rv0;
        *reinterpret_cast<bf16x8*>((char*)&Vt[buf][0] + sb1) = rv1;
        __syncthreads();
        // ---- issue next tile's global loads (latency hides under compute) ----
        if (t + 1 < ntile) {
            const int j1 = j0 + 64;
            const unsigned short* kp = Kb + (size_t)(j1 + srow) * DHEAD + c0;
            const unsigned short* vp = Vb + (size_t)srow * SEQ + j1 + c0;
            rk0 = *reinterpret_cast<const bf16x8*>(kp);
            rk1 = *reinterpret_cast<const bf16x8*>(kp + 8);
            rv0 = *reinterpret_cast<const bf16x8*>(vp);
            rv1 = *reinterpret_cast<const bf16x8*>(vp + 8);
        }

        if (j0 <= wr0 + 31) {
            // ---- S^T = K * Q^T ----
            f32x16 S[2];
#pragma unroll
            for (int r = 0; r < 16; ++r) { S[0][r] = 0.f; S[1][r] = 0.f; }
            __builtin_amdgcn_s_setprio(1);
#pragma unroll
            for (int kb = 0; kb < 2; ++kb) {
                const int key = kb * 32 + qcol;
#pragma unroll
                for (int ksub = 0; ksub < 4; ++ksub) {
                    int boff = key * 128 + ((ksub * 32 + hlf * 16) ^ ((key & 7) << 4));
                    bf16x8 kf = *reinterpret_cast<const bf16x8*>((char*)&Ks[buf][0] + boff);
                    S[kb] = __builtin_amdgcn_mfma_f32_32x32x16_bf16(
                        kf, qf[ksub], S[kb], 0, 0, 0);
                }
            }
            __builtin_amdgcn_s_setprio(0);

            // ---- causal mask (boundary tiles only) ----
            if (j0 + 63 > wr0) {
#pragma unroll
                for (int kb = 0; kb < 2; ++kb)
#pragma unroll
                    for (int r = 0; r < 16; ++r) {
                        int ka = j0 + kb * 32 + (r & 3) + 8 * (r >> 2) + 4 * hlf;
                        if (ka > qrow) S[kb][r] = -1e30f;
                    }
            }

            // ---- softmax (exp2 domain): in-register reduce + 1 shfl ----
            float pm = S[0][0];
#pragma unroll
            for (int r = 1; r < 16; ++r) pm = fmaxf(pm, S[0][r]);
#pragma unroll
            for (int r = 0; r < 16; ++r) pm = fmaxf(pm, S[1][r]);
            pm = fmaxf(pm, __shfl_xor(pm, 32));

            if (__any(pm > m)) {
                float mnew = fmaxf(m, pm);
                float cor  = __builtin_amdgcn_exp2f(m - mnew);
                m = mnew;
                l *= cor;
#pragma unroll
                for (int r = 0; r < 16; ++r) { O0[r] *= cor; O1[r] *= cor; }
            }

            float ls = 0.f;
#pragma unroll
            for (int kb = 0; kb < 2; ++kb)
#pragma unroll
                for (int r = 0; r < 16; ++r) {
                    float p = __builtin_amdgcn_exp2f(S[kb][r] - m);
                    S[kb][r] = p;
                    ls += p;
                }
            l += ls;

            // ---- PV: O^T += V^T * P^T (cvt_pk + permlane swap) ----
#pragma unroll
            for (int kc = 0; kc < 4; ++kc) {
                const int kb = kc >> 1;
                const int R0 = (kc & 1) * 8;
                unsigned pa = cvt_pk_bf16(S[kb][R0 + 0], S[kb][R0 + 1]);
                unsigned pc = cvt_pk_bf16(S[kb][R0 + 4], S[kb][R0 + 5]);
                asm("v_permlane32_swap_b32 %0, %1" : "+v"(pa), "+v"(pc));
                unsigned pb = cvt_pk_bf16(S[kb][R0 + 2], S[kb][R0 + 3]);
                unsigned pd = cvt_pk_bf16(S[kb][R0 + 6], S[kb][R0 + 7]);
                asm("v_permlane32_swap_b32 %0, %1" : "+v"(pb), "+v"(pd));
                union { unsigned u[4]; bf16x8 v; } pf;
                pf.u[0] = pa; pf.u[1] = pb; pf.u[2] = pc; pf.u[3] = pd;
                __builtin_amdgcn_s_setprio(1);
#pragma unroll
                for (int db = 0; db < 2; ++db) {
                    const int dim = db * 32 + qcol;
                    int boff = dim * 128 + ((kc * 32 + hlf * 16) ^ ((dim & 7) << 4));
                    bf16x8 vf = *reinterpret_cast<const bf16x8*>((char*)&Vt[buf][0] + boff);
                    if (db == 0)
                        O0 = __builtin_amdgcn_mfma_f32_32x32x16_bf16(vf, pf.v, O0, 0, 0, 0);
                    else
                        O1 = __builtin_amdgcn_mfma_f32_32x32x16_bf16(vf, pf.v, O1, 0, 0, 0);
                }
                __builtin_amdgcn_s_setprio(0);
            }
        }
    }

    // ---- epilogue ----
    l += __shfl_xor(l, 32);
    const float inv = 1.f / l;
    unsigned short* crow = CTX + ((size_t)(b * SEQ + qrow)) * DMODEL + h * DHEAD;
#pragma unroll
    for (int pq = 0; pq < 4; ++pq) {
        unsigned w0 = cvt_pk_bf16(O0[pq * 4 + 0] * inv, O0[pq * 4 + 1] * inv);
        unsigned w1 = cvt_pk_bf16(O0[pq * 4 + 2] * inv, O0[pq * 4 + 3] * inv);
        uint2 val; val.x = w0; val.y = w1;
        *reinterpret_cast<uint2*>(crow + 8 * pq + 4 * hlf) = val;
    }
#pragma unroll
    for (int pq = 0; pq < 4; ++pq) {
        unsigned w0 = cvt_pk_bf16(O1[pq * 4 + 0] * inv, O1[pq * 4 + 1] * inv);
        unsigned w1 = cvt_pk_bf16(O1[pq * 4 + 2] * inv, O1[pq * 4 + 3] * inv);
        uint2 val; val.x = w0; val.y = w1;
        *reinterpret_cast<uint2*>(crow + 32 + 8 * pq + 4 * hlf) = val;
    }
}

// ---------------------------------------------------------------------------
extern "C" void kernel_launch(void* const* d_in, const int* in_sizes, int n_in,
                              void* d_out, int out_size, void* d_ws, size_t ws_size,
                              hipStream_t stream) {
    const float* hs = (const float*)d_in[0];
    const float* Wq = (const float*)d_in[1];
    const float* bq = (const float*)d_in[2];
    const float* Wk = (const float*)d_in[3];
    const float* bk = (const float*)d_in[4];
    const float* Wv = (const float*)d_in[5];
    const float* bv = (const float*)d_in[6];
    const float* Wo = (const float*)d_in[7];
    const float* bo = (const float*)d_in[8];
    float* out = (float*)d_out;

    const size_t NTOK = (size_t)NBATCH * SEQ;        // 4096
    unsigned short* hs_bf  = (unsigned short*)d_ws;              // 8 MB
    unsigned short* Wqkv_t = hs_bf + NTOK * DMODEL;              // 6 MB [3072][1024]
    unsigned short* Wo_t   = Wqkv_t + 3072 * 1024;               // 2 MB [1024][1024]
    unsigned short* Qh     = Wo_t + 1024 * 1024;                 // 8 MB [B,H,S,64]
    unsigned short* Kh     = Qh + NTOK * DMODEL;                 // 8 MB
    unsigned short* Vt     = Kh + NTOK * DMODEL;                 // 8 MB [B,H,64,S]
    unsigned short* Cb     = Vt + NTOK * DMODEL;                 // 8 MB ctx bf16

    cast_bf16_kernel<<<(int)(NTOK * DMODEL / 8 / 256), 256, 0, stream>>>(hs, hs_bf);
    wt_cast_kernel<<<256, 256, 0, stream>>>(Wq, Wqkv_t);
    wt_cast_kernel<<<256, 256, 0, stream>>>(Wk, Wqkv_t + 1024 * 1024);
    wt_cast_kernel<<<256, 256, 0, stream>>>(Wv, Wqkv_t + 2 * 1024 * 1024);
    wt_cast_kernel<<<256, 256, 0, stream>>>(Wo, Wo_t);

    dim3 gqkv(3072 / 128, NTOK / 128);               // (24, 32)
    gemm_bf16<0><<<gqkv, 256, 0, stream>>>(hs_bf, Wqkv_t, bq, bk, bv,
                                           nullptr, Qh, Kh, Vt,
                                           (int)NTOK, 3072, DMODEL);

    attn_mfma_kernel<<<NBATCH * NHEADS * (SEQ / 128), 256, 0, stream>>>(Qh, Kh, Vt, Cb);

    dim3 go(DMODEL / 128, NTOK / 128);               // (8, 32)
    gemm_bf16<1><<<go, 256, 0, stream>>>(Cb, Wo_t, bo, nullptr, nullptr,
                                         out, nullptr, nullptr, nullptr,
                                         (int)NTOK, DMODEL, DMODEL);
}